// Round 22
// baseline (91.033 us; speedup 1.0000x reference)
//
#include <hip/hip_runtime.h>
#include <math.h>

#define NB 4
#define NH 512
#define NW 512
#define NC 19
#define NPIX (NB*NH*NW)
#define TS 16
#define NLAD 128
#define INF6 1.0e6f
#define MAXDIS 1.0e5f
#define NWRD 16          // 512 rows / 32 bits
#define NREP 8           // histogram replicas
#define HSTRIDE 132      // padded per-replica stride (129 bins)
#define NVD (NB*NH)      // vdist blocks in k2 (2048)
#define NKL2 (NB*NH/2)   // kl pair-blocks in k2 (1024, two rows each)
#define NT3 ((NW/TS)*(NH/TS)*NB)      // k3 blocks = 4096
#define NZERO2 (NREP*HSTRIDE)         // hist words zeroed by k1 block 0

// Compile-time eps ladder: bit-exact IEEE float chain (e = 1e-5f; e *= 1.2f).
struct Lad { float v[NLAD]; };
static constexpr Lad make_lad() {
    Lad t{};
    float e = 1e-5f;
    for (int k = 0; k < NLAD; ++k) { t.v[k] = e; e *= 1.2f; }
    return t;
}
__constant__ Lad LADC = make_lad();

// 19-float run as 5 overlapping float4s (4B alignment is sufficient).
__device__ __forceinline__ void load19(const float* __restrict__ base, float (&v)[NC]) {
    float4 q0 = *reinterpret_cast<const float4*>(base);
    float4 q1 = *reinterpret_cast<const float4*>(base + 4);
    float4 q2 = *reinterpret_cast<const float4*>(base + 8);
    float4 q3 = *reinterpret_cast<const float4*>(base + 12);
    float4 q4 = *reinterpret_cast<const float4*>(base + 15);
    v[0]=q0.x; v[1]=q0.y; v[2]=q0.z; v[3]=q0.w;
    v[4]=q1.x; v[5]=q1.y; v[6]=q1.z; v[7]=q1.w;
    v[8]=q2.x; v[9]=q2.y; v[10]=q2.z; v[11]=q2.w;
    v[12]=q3.x; v[13]=q3.y; v[14]=q3.z; v[15]=q3.w;
    v[16]=q4.y; v[17]=q4.z; v[18]=q4.w;
}

// Sequential LSE, bit-identical to the established formula.
__device__ __forceinline__ float lse19(const float (&v)[NC]) {
    float mx = v[0];
#pragma unroll
    for (int c = 1; c < NC; ++c) mx = fmaxf(mx, v[c]);
    float se = 0.f;
#pragma unroll
    for (int c = 0; c < NC; ++c) se += expf(v[c] - mx);
    return mx + logf(se);
}

// ---------------------------------------------------------------------------
// k1: boundary bitmasks only (LSE pass deleted -- k2 computes LSEs in-pair,
// k3 inline). Block 0 zeroes hist.
// ---------------------------------------------------------------------------
__global__ __launch_bounds__(64) void k1_kernel(const int* __restrict__ tgt,
                                                unsigned int* __restrict__ maskw,
                                                unsigned int* __restrict__ zbuf) {
    const int tid = threadIdx.x;
    if (blockIdx.x == 0) {
        for (int k = tid; k < NZERO2; k += 64) zbuf[k] = 0u;
    }
    const int cidx = blockIdx.x * 64 + tid;            // [b][w][j]
    const int j = cidx & (NW - 1);
    const int w = (cidx >> 9) & (NWRD - 1);
    const int b = cidx >> 13;
    const int* t = tgt + (size_t)b * NH * NW;
    unsigned int mask = 0u;
    const int i0 = w * 32;
    int cur = t[(size_t)i0 * NW + j];
    for (int k = 0; k < 32; ++k) {
        int i = i0 + k;
        int nxt = (i + 1 < NH) ? t[(size_t)(i + 1) * NW + j] : cur;
        bool bnd = (cur == 255);
        if (i + 1 < NH && nxt != cur) bnd = true;
        if (j + 1 < NW && t[(size_t)i * NW + j + 1] != cur) bnd = true;
        if (bnd) mask |= (1u << k);
        cur = nxt;
    }
    maskw[cidx] = mask;
}

// ---------------------------------------------------------------------------
// k2: vertical-dist + row min-plus (blocks 0..NVD-1) PARALLEL WITH kl map +
// fused replica histogram (pair-blocks: two rows each). Row 2k's lse_d is
// row 2k+1's in-register lse_c (and its down VECTOR is the already-loaded
// lc1); only row 2k+2's LSE is recomputed (1.5x total vs round 18's 2x).
// lse_r via LDS share. Pair-blocks XCD-chunk swizzled (bijective, 1024%8==0).
// ---------------------------------------------------------------------------
__global__ __launch_bounds__(512) void k2_kernel(const unsigned int* __restrict__ maskw,
                                                 const float* __restrict__ logits,
                                                 float* __restrict__ dist,
                                                 float* __restrict__ klb,
                                                 unsigned int* __restrict__ hist) {
    __shared__ unsigned int smw[NWRD][NW];   // 32 KB (vdist branch)
    __shared__ float srow[NW];
    __shared__ unsigned int anyw[8];
    __shared__ float lseA[NW];               // kl branch: row-pair LSE shares
    __shared__ float lseB[NW];
    __shared__ float lad[NLAD];
    __shared__ unsigned int lh[NLAD + 1];
    const int tid = threadIdx.x;

    if (blockIdx.x < NVD) {
        const int row = blockIdx.x;              // b*NH + i
        const int b = row >> 9;
        const int i = row & (NH - 1);
        const unsigned int* mcol = maskw + (size_t)b * NWRD * NW;
        unsigned int acc = 0u;
#pragma unroll
        for (int w = 0; w < NWRD; ++w) {
            unsigned int v = mcol[w * NW + tid];
            smw[w][tid] = v;
            acc |= v;
        }
        unsigned long long bal = __ballot(acc != 0u);
        if ((tid & 63) == 0) anyw[tid >> 6] = (bal != 0ull) ? 1u : 0u;

        const int wi = i >> 5, bi = i & 31;
        int down = 1 << 20;
        unsigned int m = smw[wi][tid] & ((2u << bi) - 1u);
        if (m) down = bi - (31 - __clz(m));
        else {
            for (int w = wi - 1; w >= 0; --w) {
                unsigned int mm = smw[w][tid];
                if (mm) { down = bi + 32 * (wi - w) - (31 - __clz(mm)); break; }
            }
        }
        int up = 1 << 20;
        unsigned int mu = smw[wi][tid] & ~((1u << bi) - 1u);
        if (mu) up = (__ffs(mu) - 1) - bi;
        else {
            for (int w = wi + 1; w < NWRD; ++w) {
                unsigned int mm = smw[w][tid];
                if (mm) { up = 32 * (w - wi) + (__ffs(mm) - 1) - bi; break; }
            }
        }
        int gi = min(down, up);
        float G = (gi >= (1 << 20)) ? INF6 : (float)gi;
        srow[tid] = G * G;
        __syncthreads();
        bool has = (anyw[0] | anyw[1] | anyw[2] | anyw[3] |
                    anyw[4] | anyw[5] | anyw[6] | anyw[7]) != 0u;
        float best = srow[tid];
        for (int r = 1; r < NW; ++r) {
            float rr = (float)(r * r);
            if (rr >= best) break;
            int jl = tid - r, jr = tid + r;
            if (jl >= 0) best = fminf(best, srow[jl] + rr);
            if (jr < NW) best = fminf(best, srow[jr] + rr);
        }
        dist[(size_t)row * NW + tid] = has ? fmaxf(sqrtf(best) - 1.f, 0.f) : 0.f;
    } else {
        if (tid < NLAD) lad[tid] = LADC.v[tid];
        if (tid < NLAD + 1) lh[tid] = 0u;

        const int kb = blockIdx.x - NVD;                 // [0, 1024)
        const int rp = ((kb & 7) << 7) | (kb >> 3);      // XCD-chunk swizzle
        const int r0 = rp * 2;                           // even flat row
        const int i0 = r0 & (NH - 1);                    // even -> <= 510
        const int j = tid;
        const size_t p0 = (size_t)r0 * NW + j;
        const size_t p1 = p0 + NW;
        const bool hasr = (j < NW - 1);
        const bool hasd1 = (i0 + 1 < NH - 1);            // row1 has a down row
        const float* b0 = logits + p0 * NC;
        const float* b1 = logits + p1 * NC;
        const int offr = hasr ? NC : 0;                  // clamp: in-bounds
        const int offd1 = hasd1 ? NW * NC : 0;

        float lc0[NC];
        load19(b0, lc0);
        float lc1[NC];
        load19(b1, lc1);
        const float lse0 = lse19(lc0);
        const float lse1 = lse19(lc1);
        lseA[tid] = lse0;
        lseB[tid] = lse1;
        __syncthreads();
        const float lse_r0 = hasr ? lseA[tid + 1] : 0.f;
        const float lse_r1 = hasr ? lseB[tid + 1] : 0.f;

        // ---- row 0: down row is lc1 (in regs), lse_d = lse1
        {
            float pc[NC];
            float negH = 0.f;
#pragma unroll
            for (int c = 0; c < NC; ++c) {
                float s = lc0[c] - lse0;
                float e = expf(s);
                pc[c] = e;
                negH += e * s;
            }
            float lr[NC];
            load19(b0 + offr, lr);
            float dotr = 0.f;
#pragma unroll
            for (int c = 0; c < NC; ++c) dotr += pc[c] * lr[c];
            float dotd = 0.f;
#pragma unroll
            for (int c = 0; c < NC; ++c) dotd += pc[c] * lc1[c];
            float kl = negH + lse1 - dotd;               // hasd0 always true
            if (hasr) kl += negH + lse_r0 - dotr;
            klb[p0] = kl;
            int lo = 0, hi = NLAD;
            while (lo < hi) { int mid = (lo + hi) >> 1; if (kl > lad[mid]) lo = mid + 1; else hi = mid; }
            atomicAdd(&lh[lo], 1u);
        }
        // ---- row 1: down row loaded, lse_d computed here (the only extra LSE)
        {
            float ld1[NC];
            load19(b1 + offd1, ld1);
            const float lse2 = hasd1 ? lse19(ld1) : 0.f;
            float pc[NC];
            float negH = 0.f;
#pragma unroll
            for (int c = 0; c < NC; ++c) {
                float s = lc1[c] - lse1;
                float e = expf(s);
                pc[c] = e;
                negH += e * s;
            }
            float lr[NC];
            load19(b1 + offr, lr);
            float dotr = 0.f;
#pragma unroll
            for (int c = 0; c < NC; ++c) dotr += pc[c] * lr[c];
            float dotd = 0.f;
#pragma unroll
            for (int c = 0; c < NC; ++c) dotd += pc[c] * ld1[c];
            float kl = 0.f;
            if (hasd1) kl += negH + lse2 - dotd;
            if (hasr) kl += negH + lse_r1 - dotr;
            klb[p1] = kl;
            int lo = 0, hi = NLAD;
            while (lo < hi) { int mid = (lo + hi) >> 1; if (kl > lad[mid]) lo = mid + 1; else hi = mid; }
            atomicAdd(&lh[lo], 1u);
        }
        __syncthreads();
        if (tid < NLAD + 1 && lh[tid])
            atomicAdd(&hist[(blockIdx.x & (NREP - 1)) * HSTRIDE + tid], lh[tid]);
    }
}

// ---------------------------------------------------------------------------
// k3: parallel eps (Hillis-Steele suffix scan + ballot) + validity on LDS
// tiles + in-block compaction + 8-lane CE (LSEs inline, round-19 code) +
// block reduce. Per-block partials to distinct slots (no global atomics).
// ---------------------------------------------------------------------------
__global__ __launch_bounds__(256) void k3_kernel(const float* __restrict__ klb,
                                                 const float* __restrict__ dist,
                                                 const float* __restrict__ logits,
                                                 const unsigned int* __restrict__ hist,
                                                 float* __restrict__ partials,
                                                 unsigned int* __restrict__ bcnt) {
    __shared__ unsigned int suf[NLAD + 1];   // 129 suffix sums (in-place scan)
    __shared__ unsigned int wcnt[4];
    __shared__ float epsS;
    __shared__ float klT[18][19];
    __shared__ float dsT[18][19];
    __shared__ unsigned int ent[256];
    __shared__ unsigned int nvS;
    __shared__ float rs[256];
    const int tid = threadIdx.x;
    if (tid < NLAD + 1) {
        unsigned int s = 0;
        for (int r = 0; r < NREP; ++r) s += hist[r * HSTRIDE + tid];
        suf[tid] = s;
    }
    if (tid == 0) nvS = 0u;
    if (tid < 4) wcnt[tid] = 0u;

    const int b = blockIdx.z;
    const int i0 = blockIdx.y * TS;
    const int j0 = blockIdx.x * TS;
    const float* klp = klb + (size_t)b * NH * NW;
    const float* dp = dist + (size_t)b * NH * NW;

    // stage 18x18 kl + dist tiles (halo-clamped sentinels)
    for (int t = tid; t < 324; t += 256) {
        const int r = t / 18, c = t % 18;
        const int ii = i0 - 1 + r, jj = j0 - 1 + c;
        const bool inb = (ii >= 0 && ii < NH && jj >= 0 && jj < NW);
        klT[r][c] = inb ? klp[(size_t)ii * NW + jj] : -1.f;
        dsT[r][c] = inb ? dp[(size_t)ii * NW + jj] : MAXDIS;
    }
    __syncthreads();

    // parallel suffix scan over suf[0..128] (integer, exact, 8 steps)
#pragma unroll
    for (int step = 1; step <= 128; step <<= 1) {
        unsigned int val = 0u;
        if (tid <= NLAD) {
            val = suf[tid];
            if (tid + step <= NLAD) val += suf[tid + step];
        }
        __syncthreads();
        if (tid <= NLAD) suf[tid] = val;
        __syncthreads();
    }
    {
        bool flag = (tid < NLAD - 1) && ((float)suf[tid + 1] > 2621.44f);
        unsigned long long mk = __ballot(flag);
        if ((tid & 63) == 0) wcnt[tid >> 6] = (unsigned int)__popcll(mk);
        __syncthreads();
        if (tid == 0) epsS = LADC.v[wcnt[0] + wcnt[1] + wcnt[2] + wcnt[3]];
        __syncthreads();
    }
    const float eps = epsS;

    const int ty = tid >> 4, tx = tid & 15;
    const int i = i0 + ty, j = j0 + tx;

    bool pb = false;
#pragma unroll
    for (int r = 0; r < 3; ++r)
#pragma unroll
        for (int c = 0; c < 3; ++c)
            if (klT[ty + r][tx + c] > eps) pb = true;

    const int dxs[9] = {1, -1, 0, 0, -1, 1, -1, 1, 0};
    const int dys[9] = {0, 0, -1, 1, 1, 1, -1, -1, 0};
    float best = MAXDIS; int gidx = 0;
#pragma unroll
    for (int k = 0; k < 9; ++k) {
        float v = dsT[ty + 1 + dxs[k]][tx + 1 + dys[k]];
        if (k == 0) { best = v; gidx = 0; }
        else if (v < best) { best = v; gidx = k; }
    }
    const bool valid = pb && (gidx != 8);
    const int pix = (b * NH + i) * NW + j;

    // in-block compaction (LDS atomic only); store tile tid for dist reuse
    const int lane = tid & 63;
    unsigned long long mk = __ballot(valid);
    int cnt = __popcll(mk);
    unsigned int base = 0u;
    if (lane == 0 && cnt) base = atomicAdd(&nvS, (unsigned int)cnt);
    base = (unsigned int)__shfl((int)base, 0, 64);
    if (valid)
        ent[base + (unsigned int)__popcll(mk & ((1ull << lane) - 1ull))] =
            (unsigned int)pix | ((unsigned int)gidx << 20) | ((unsigned int)tid << 24);
    __syncthreads();
    const int nv = (int)nvS;

    // CE over compacted entries: 32 groups x 8 lanes; LSEs inline
    float acc = 0.f;
    const int grp = tid >> 3, d = tid & 7;
    for (int e = grp; e < nv; e += 32) {
        const unsigned int w = ent[e];
        const int epix = (int)(w & (NPIX - 1));
        const int egidx = (int)((w >> 20) & 15u);
        const int etid = (int)(w >> 24);
        const int ej = epix & (NW - 1);
        const int ei = (epix >> 9) & (NH - 1);

        const unsigned int DXP = (2u<<0)|(0u<<2)|(1u<<4)|(1u<<6)|(0u<<8)|(2u<<10)|(0u<<12)|(2u<<14);
        const unsigned int DYP = (1u<<0)|(1u<<2)|(0u<<4)|(2u<<6)|(2u<<8)|(2u<<10)|(0u<<12)|(0u<<14);
        const int dx = (int)((DXP >> (2 * d)) & 3u) - 1;
        const int dy = (int)((DYP >> (2 * d)) & 3u) - 1;
        const int ii = ei + dx, jj = ej + dy;
        const bool inb = (ii >= 0 && ii < NH && jj >= 0 && jj < NW);

        const float* lcp = logits + (size_t)epix * NC;
        float lc[NC];
        load19(lcp, lc);
        float sumlc = 0.f;
#pragma unroll
        for (int c = 0; c < NC; ++c) sumlc += lc[c];
        const float lse_c = lse19(lc);

        float klm;
        if (inb) {
            const int npix = epix + dx * NW + dy;
            const float* lnp = logits + (size_t)npix * NC;
            float ln[NC];
            load19(lnp, ln);
            const float lse_n = lse19(ln);
            float negH = 0.f, dot = 0.f;
#pragma unroll
            for (int c = 0; c < NC; ++c) {
                float sv = ln[c] - lse_n;
                float p = expf(sv);
                negH += p * sv;
                dot += p * lc[c];
            }
            klm = negH + lse_c - dot;
        } else {
            klm = -logf(19.f) + lse_c - sumlc / 19.f;
        }

        float m2 = klm;
#pragma unroll
        for (int o = 4; o > 0; o >>= 1) m2 = fmaxf(m2, __shfl_xor(m2, o, 8));
        float ex = expf(klm - m2);
        float s2 = ex;
#pragma unroll
        for (int o = 4; o > 0; o >>= 1) s2 += __shfl_xor(s2, o, 8);
        float lse = m2 + logf(s2);
        float lp = klm - lse;
        float slp = lp;
#pragma unroll
        for (int o = 4; o > 0; o >>= 1) slp += __shfl_xor(slp, o, 8);
        float kg = (d == egidx) ? lp : 0.f;
#pragma unroll
        for (int o = 4; o > 0; o >>= 1) kg += __shfl_xor(kg, o, 8);

        if (d == 0) {
            float ce = -(0.2f / 8.f) * slp - 0.8f * kg;
            float wgt = fminf(dsT[(etid >> 4) + 1][(etid & 15) + 1], 20.f) / 20.f;
            acc += ce * wgt;
        }
    }
    rs[tid] = acc;
    __syncthreads();
    for (int q = 128; q > 0; q >>= 1) {
        if (tid < q) rs[tid] += rs[tid + q];
        __syncthreads();
    }
    if (tid == 0) {
        const int bid = (blockIdx.z * gridDim.y + blockIdx.y) * gridDim.x + blockIdx.x;
        partials[bid] = rs[0];
        bcnt[bid] = (unsigned int)nv;
    }
}

// ---------------------------------------------------------------------------
// k4: fixed-order reduce of 4096 partials + 4096 counts -> loss.
// ---------------------------------------------------------------------------
__global__ __launch_bounds__(256) void k4_kernel(const float* __restrict__ partials,
                                                 const unsigned int* __restrict__ bcnt,
                                                 float* __restrict__ out) {
    __shared__ float r1[256];
    __shared__ unsigned int r2[256];
    const int tid = threadIdx.x;
    float s = 0.f;
    unsigned int c = 0u;
#pragma unroll
    for (int q = 0; q < NT3 / 256; ++q) {
        s += partials[tid + q * 256];
        c += bcnt[tid + q * 256];
    }
    r1[tid] = s; r2[tid] = c;
    __syncthreads();
    for (int q = 128; q > 0; q >>= 1) {
        if (tid < q) { r1[tid] += r1[tid + q]; r2[tid] += r2[tid + q]; }
        __syncthreads();
    }
    if (tid == 0) out[0] = r1[0] / fmaxf((float)r2[0], 1.f);
}

extern "C" void kernel_launch(void* const* d_in, const int* in_sizes, int n_in,
                              void* d_out, int out_size, void* d_ws, size_t ws_size,
                              hipStream_t stream) {
    const float* logits = (const float*)d_in[0];
    const int* target = (const int*)d_in[1];
    float* out = (float*)d_out;

    float* fws = (float*)d_ws;
    float* distb = fws;                         // NPIX floats
    float* klb = fws + NPIX;                    // NPIX floats
    unsigned int* hist = (unsigned int*)(fws + 2 * (size_t)NPIX);   // NREP*HSTRIDE
    float* partials = (float*)(hist + NREP * HSTRIDE);              // NT3
    unsigned int* bcnt = (unsigned int*)(partials + NT3);           // NT3
    unsigned int* maskw = bcnt + NT3;                               // NB*NWRD*NW

    // k1: bound bitmasks (+zero hist)
    k1_kernel<<<NB * NWRD * NW / 64, 64, 0, stream>>>(target, maskw, hist);
    // k2: vdist+rowmin || kl pair-blocks (1.5x inline LSE, XCD-chunked)
    k2_kernel<<<NVD + NKL2, 512, 0, stream>>>(maskw, logits, distb, klb, hist);
    // k3: parallel-eps + valid (LDS tiles) + in-block CE (inline LSE)
    dim3 tiles(NW / TS, NH / TS, NB);
    k3_kernel<<<tiles, 256, 0, stream>>>(klb, distb, logits, hist, partials, bcnt);
    // k4: deterministic final reduce
    k4_kernel<<<1, 256, 0, stream>>>(partials, bcnt, out);
}

// Round 23
// 82.278 us; speedup vs baseline: 1.1064x; 1.1064x over previous
//
#include <hip/hip_runtime.h>
#include <math.h>

#define NB 4
#define NH 512
#define NW 512
#define NC 19
#define NPIX (NB*NH*NW)
#define TS 16
#define NLAD 128
#define INF6 1.0e6f
#define MAXDIS 1.0e5f
#define NWRD 16          // 512 rows / 32 bits
#define NREP 8           // histogram replicas
#define HSTRIDE 132      // padded per-replica stride (129 bins)
#define NBND 128         // bound blocks in k1 (32768 items / 256)
#define NVD (NB*NH)      // vdist blocks in k2 (2048)
#define NKL (NPIX/512)   // kl blocks in k2 (2048, one image row each)
#define NT3 ((NW/TS)*(NH/TS)*NB)      // k3 blocks = 4096
#define NZERO2 (NREP*HSTRIDE)         // hist words zeroed by k1 block 0

// Compile-time eps ladder: bit-exact IEEE float chain (e = 1e-5f; e *= 1.2f).
struct Lad { float v[NLAD]; };
static constexpr Lad make_lad() {
    Lad t{};
    float e = 1e-5f;
    for (int k = 0; k < NLAD; ++k) { t.v[k] = e; e *= 1.2f; }
    return t;
}
__constant__ Lad LADC = make_lad();

// 19-float run as 5 overlapping float4s (4B alignment is sufficient).
__device__ __forceinline__ void load19(const float* __restrict__ base, float (&v)[NC]) {
    float4 q0 = *reinterpret_cast<const float4*>(base);
    float4 q1 = *reinterpret_cast<const float4*>(base + 4);
    float4 q2 = *reinterpret_cast<const float4*>(base + 8);
    float4 q3 = *reinterpret_cast<const float4*>(base + 12);
    float4 q4 = *reinterpret_cast<const float4*>(base + 15);
    v[0]=q0.x; v[1]=q0.y; v[2]=q0.z; v[3]=q0.w;
    v[4]=q1.x; v[5]=q1.y; v[6]=q1.z; v[7]=q1.w;
    v[8]=q2.x; v[9]=q2.y; v[10]=q2.z; v[11]=q2.w;
    v[12]=q3.x; v[13]=q3.y; v[14]=q3.z; v[15]=q3.w;
    v[16]=q4.y; v[17]=q4.z; v[18]=q4.w;
}

// ---------------------------------------------------------------------------
// k1: boundary bitmasks (blocks 0..NBND-1) PARALLEL WITH per-pixel LSE map
// (remaining blocks; each LSE computed exactly once). Block 0 zeroes hist.
// ---------------------------------------------------------------------------
__global__ __launch_bounds__(256) void k1_kernel(const int* __restrict__ tgt,
                                                 const float* __restrict__ logits,
                                                 unsigned int* __restrict__ maskw,
                                                 float* __restrict__ lsem,
                                                 unsigned int* __restrict__ zbuf) {
    const int tid = threadIdx.x;
    if (blockIdx.x < NBND) {
        if (blockIdx.x == 0) {
            for (int k = tid; k < NZERO2; k += 256) zbuf[k] = 0u;
        }
        const int cidx = blockIdx.x * 256 + tid;       // [b][w][j]
        const int j = cidx & (NW - 1);
        const int w = (cidx >> 9) & (NWRD - 1);
        const int b = cidx >> 13;
        const int* t = tgt + (size_t)b * NH * NW;
        unsigned int mask = 0u;
        const int i0 = w * 32;
        int cur = t[(size_t)i0 * NW + j];
        for (int k = 0; k < 32; ++k) {
            int i = i0 + k;
            int nxt = (i + 1 < NH) ? t[(size_t)(i + 1) * NW + j] : cur;
            bool bnd = (cur == 255);
            if (i + 1 < NH && nxt != cur) bnd = true;
            if (j + 1 < NW && t[(size_t)i * NW + j + 1] != cur) bnd = true;
            if (bnd) mask |= (1u << k);
            cur = nxt;
        }
        maskw[cidx] = mask;
    } else {
        const int p = (blockIdx.x - NBND) * 256 + tid;
        float v[NC];
        load19(logits + (size_t)p * NC, v);
        float mx = v[0];
#pragma unroll
        for (int c = 1; c < NC; ++c) mx = fmaxf(mx, v[c]);
        float se = 0.f;
#pragma unroll
        for (int c = 0; c < NC; ++c) se += expf(v[c] - mx);
        lsem[p] = mx + logf(se);
    }
}

// ---------------------------------------------------------------------------
// k2: vertical-dist + row min-plus (blocks 0..NVD-1) PARALLEL WITH kl map +
// fused replica histogram (remaining blocks). LSEs from lsem. kl blocks are
// XCD-chunk swizzled (row = (kb&7)*256 + kb>>3, bijective): each XCD gets a
// contiguous 256-row span so the down-row read is an L2 hit.
// ---------------------------------------------------------------------------
__global__ __launch_bounds__(512) void k2_kernel(const unsigned int* __restrict__ maskw,
                                                 const float* __restrict__ logits,
                                                 const float* __restrict__ lsem,
                                                 float* __restrict__ dist,
                                                 float* __restrict__ klb,
                                                 unsigned int* __restrict__ hist) {
    __shared__ unsigned int smw[NWRD][NW];   // 32 KB (vdist branch)
    __shared__ float srow[NW];
    __shared__ unsigned int anyw[8];
    __shared__ float lad[NLAD];              // kl branch
    __shared__ unsigned int lh[NLAD + 1];
    const int tid = threadIdx.x;

    if (blockIdx.x < NVD) {
        const int row = blockIdx.x;              // b*NH + i
        const int b = row >> 9;
        const int i = row & (NH - 1);
        const unsigned int* mcol = maskw + (size_t)b * NWRD * NW;
        unsigned int acc = 0u;
#pragma unroll
        for (int w = 0; w < NWRD; ++w) {
            unsigned int v = mcol[w * NW + tid];
            smw[w][tid] = v;
            acc |= v;
        }
        unsigned long long bal = __ballot(acc != 0u);
        if ((tid & 63) == 0) anyw[tid >> 6] = (bal != 0ull) ? 1u : 0u;

        const int wi = i >> 5, bi = i & 31;
        int down = 1 << 20;
        unsigned int m = smw[wi][tid] & ((2u << bi) - 1u);
        if (m) down = bi - (31 - __clz(m));
        else {
            for (int w = wi - 1; w >= 0; --w) {
                unsigned int mm = smw[w][tid];
                if (mm) { down = bi + 32 * (wi - w) - (31 - __clz(mm)); break; }
            }
        }
        int up = 1 << 20;
        unsigned int mu = smw[wi][tid] & ~((1u << bi) - 1u);
        if (mu) up = (__ffs(mu) - 1) - bi;
        else {
            for (int w = wi + 1; w < NWRD; ++w) {
                unsigned int mm = smw[w][tid];
                if (mm) { up = 32 * (w - wi) + (__ffs(mm) - 1) - bi; break; }
            }
        }
        int gi = min(down, up);
        float G = (gi >= (1 << 20)) ? INF6 : (float)gi;
        srow[tid] = G * G;
        __syncthreads();
        bool has = (anyw[0] | anyw[1] | anyw[2] | anyw[3] |
                    anyw[4] | anyw[5] | anyw[6] | anyw[7]) != 0u;
        float best = srow[tid];
        for (int r = 1; r < NW; ++r) {
            float rr = (float)(r * r);
            if (rr >= best) break;
            int jl = tid - r, jr = tid + r;
            if (jl >= 0) best = fminf(best, srow[jl] + rr);
            if (jr < NW) best = fminf(best, srow[jr] + rr);
        }
        dist[(size_t)row * NW + tid] = has ? fmaxf(sqrtf(best) - 1.f, 0.f) : 0.f;
    } else {
        if (tid < NLAD) lad[tid] = LADC.v[tid];
        if (tid < NLAD + 1) lh[tid] = 0u;
        __syncthreads();

        const int kb = blockIdx.x - NVD;                 // kl block index
        const int row = ((kb & 7) << 8) | (kb >> 3);     // XCD-chunk swizzle
        const int p = row * 512 + tid;                   // tid = j
        const int j = tid;
        const int i = row & (NH - 1);
        const bool hasr = (j < NW - 1), hasd = (i < NH - 1);
        const float lse_c = lsem[p];
        const float lse_r = hasr ? lsem[p + 1] : 0.f;
        const float lse_d = hasd ? lsem[p + NW] : 0.f;
        const float* base = logits + (size_t)p * NC;
        const int offr = hasr ? NC : 0;        // clamp keeps reads in-bounds
        const int offd = hasd ? NW * NC : 0;

        float lc[NC];
        load19(base, lc);
        float pc[NC];
        float negH = 0.f;
#pragma unroll
        for (int c = 0; c < NC; ++c) {
            float s = lc[c] - lse_c;
            float e = expf(s);
            pc[c] = e;
            negH += e * s;
        }
        float lr[NC];
        load19(base + offr, lr);
        float dotr = 0.f;
#pragma unroll
        for (int c = 0; c < NC; ++c) dotr += pc[c] * lr[c];
        float ld[NC];
        load19(base + offd, ld);
        float dotd = 0.f;
#pragma unroll
        for (int c = 0; c < NC; ++c) dotd += pc[c] * ld[c];

        float kl = 0.f;
        if (hasd) kl += negH + lse_d - dotd;
        if (hasr) kl += negH + lse_r - dotr;
        klb[p] = kl;

        int lo = 0, hi = NLAD;
        while (lo < hi) { int mid = (lo + hi) >> 1; if (kl > lad[mid]) lo = mid + 1; else hi = mid; }
        atomicAdd(&lh[lo], 1u);
        __syncthreads();
        if (tid < NLAD + 1 && lh[tid])
            atomicAdd(&hist[(blockIdx.x & (NREP - 1)) * HSTRIDE + tid], lh[tid]);
    }
}

// ---------------------------------------------------------------------------
// k3: eps (parallel Hillis-Steele suffix scan + ballot count) + validity on
// LDS tiles + in-block compaction + 8-lane CE + block reduce.
// ---------------------------------------------------------------------------
__global__ __launch_bounds__(256) void k3_kernel(const float* __restrict__ klb,
                                                 const float* __restrict__ dist,
                                                 const float* __restrict__ logits,
                                                 const float* __restrict__ lsem,
                                                 const unsigned int* __restrict__ hist,
                                                 float* __restrict__ partials,
                                                 unsigned int* __restrict__ bcnt) {
    __shared__ unsigned int suf[NLAD + 1];   // 129 suffix sums (in-place scan)
    __shared__ unsigned int wcnt[4];
    __shared__ float epsS;
    __shared__ float klT[18][19];
    __shared__ float dsT[18][19];
    __shared__ unsigned int ent[256];
    __shared__ unsigned int nvS;
    __shared__ float rs[256];
    const int tid = threadIdx.x;
    if (tid < NLAD + 1) {
        unsigned int s = 0;
        for (int r = 0; r < NREP; ++r) s += hist[r * HSTRIDE + tid];
        suf[tid] = s;
    }
    if (tid == 0) nvS = 0u;
    if (tid < 4) wcnt[tid] = 0u;

    const int b = blockIdx.z;
    const int i0 = blockIdx.y * TS;
    const int j0 = blockIdx.x * TS;
    const float* klp = klb + (size_t)b * NH * NW;
    const float* dp = dist + (size_t)b * NH * NW;

    // stage 18x18 kl + dist tiles (halo-clamped sentinels)
    for (int t = tid; t < 324; t += 256) {
        const int r = t / 18, c = t % 18;
        const int ii = i0 - 1 + r, jj = j0 - 1 + c;
        const bool inb = (ii >= 0 && ii < NH && jj >= 0 && jj < NW);
        klT[r][c] = inb ? klp[(size_t)ii * NW + jj] : -1.f;
        dsT[r][c] = inb ? dp[(size_t)ii * NW + jj] : MAXDIS;
    }
    __syncthreads();

    // parallel suffix scan over suf[0..128] (integer, exact, 8 steps)
#pragma unroll
    for (int step = 1; step <= 128; step <<= 1) {
        unsigned int val = 0u;
        if (tid <= NLAD) {
            val = suf[tid];
            if (tid + step <= NLAD) val += suf[tid + step];
        }
        __syncthreads();
        if (tid <= NLAD) suf[tid] = val;
        __syncthreads();
    }
    // K = #{q in [0,127) : suf[q+1] > 2621.44} (suffix non-increasing)
    {
        bool flag = (tid < NLAD - 1) && ((float)suf[tid + 1] > 2621.44f);
        unsigned long long mk = __ballot(flag);
        if ((tid & 63) == 0) wcnt[tid >> 6] = (unsigned int)__popcll(mk);
        __syncthreads();
        if (tid == 0) epsS = LADC.v[wcnt[0] + wcnt[1] + wcnt[2] + wcnt[3]];
        __syncthreads();
    }
    const float eps = epsS;

    const int ty = tid >> 4, tx = tid & 15;
    const int i = i0 + ty, j = j0 + tx;

    bool pb = false;
#pragma unroll
    for (int r = 0; r < 3; ++r)
#pragma unroll
        for (int c = 0; c < 3; ++c)
            if (klT[ty + r][tx + c] > eps) pb = true;

    const int dxs[9] = {1, -1, 0, 0, -1, 1, -1, 1, 0};
    const int dys[9] = {0, 0, -1, 1, 1, 1, -1, -1, 0};
    float best = MAXDIS; int gidx = 0;
#pragma unroll
    for (int k = 0; k < 9; ++k) {
        float v = dsT[ty + 1 + dxs[k]][tx + 1 + dys[k]];
        if (k == 0) { best = v; gidx = 0; }
        else if (v < best) { best = v; gidx = k; }
    }
    const bool valid = pb && (gidx != 8);
    const int pix = (b * NH + i) * NW + j;

    // in-block compaction (LDS atomic only); store tile tid for dist reuse
    const int lane = tid & 63;
    unsigned long long mk = __ballot(valid);
    int cnt = __popcll(mk);
    unsigned int base = 0u;
    if (lane == 0 && cnt) base = atomicAdd(&nvS, (unsigned int)cnt);
    base = (unsigned int)__shfl((int)base, 0, 64);
    if (valid)
        ent[base + (unsigned int)__popcll(mk & ((1ull << lane) - 1ull))] =
            (unsigned int)pix | ((unsigned int)gidx << 20) | ((unsigned int)tid << 24);
    __syncthreads();
    const int nv = (int)nvS;

    // CE over compacted entries: 32 groups x 8 lanes; LSEs from lsem
    float acc = 0.f;
    const int grp = tid >> 3, d = tid & 7;
    for (int e = grp; e < nv; e += 32) {
        const unsigned int w = ent[e];
        const int epix = (int)(w & (NPIX - 1));
        const int egidx = (int)((w >> 20) & 15u);
        const int etid = (int)(w >> 24);
        const int ej = epix & (NW - 1);
        const int ei = (epix >> 9) & (NH - 1);

        const unsigned int DXP = (2u<<0)|(0u<<2)|(1u<<4)|(1u<<6)|(0u<<8)|(2u<<10)|(0u<<12)|(2u<<14);
        const unsigned int DYP = (1u<<0)|(1u<<2)|(0u<<4)|(2u<<6)|(2u<<8)|(2u<<10)|(0u<<12)|(0u<<14);
        const int dx = (int)((DXP >> (2 * d)) & 3u) - 1;
        const int dy = (int)((DYP >> (2 * d)) & 3u) - 1;
        const int ii = ei + dx, jj = ej + dy;
        const bool inb = (ii >= 0 && ii < NH && jj >= 0 && jj < NW);

        const float lse_c = lsem[epix];
        const float* lcp = logits + (size_t)epix * NC;
        float lc[NC];
        load19(lcp, lc);
        float sumlc = 0.f;
#pragma unroll
        for (int c = 0; c < NC; ++c) sumlc += lc[c];

        float klm;
        if (inb) {
            const int npix = epix + dx * NW + dy;
            const float lse_n = lsem[npix];
            const float* lnp = logits + (size_t)npix * NC;
            float ln[NC];
            load19(lnp, ln);
            float negH = 0.f, dot = 0.f;
#pragma unroll
            for (int c = 0; c < NC; ++c) {
                float sv = ln[c] - lse_n;
                float p = expf(sv);
                negH += p * sv;
                dot += p * lc[c];
            }
            klm = negH + lse_c - dot;
        } else {
            klm = -logf(19.f) + lse_c - sumlc / 19.f;
        }

        float m2 = klm;
#pragma unroll
        for (int o = 4; o > 0; o >>= 1) m2 = fmaxf(m2, __shfl_xor(m2, o, 8));
        float ex = expf(klm - m2);
        float s2 = ex;
#pragma unroll
        for (int o = 4; o > 0; o >>= 1) s2 += __shfl_xor(s2, o, 8);
        float lse = m2 + logf(s2);
        float lp = klm - lse;
        float slp = lp;
#pragma unroll
        for (int o = 4; o > 0; o >>= 1) slp += __shfl_xor(slp, o, 8);
        float kg = (d == egidx) ? lp : 0.f;
#pragma unroll
        for (int o = 4; o > 0; o >>= 1) kg += __shfl_xor(kg, o, 8);

        if (d == 0) {
            float ce = -(0.2f / 8.f) * slp - 0.8f * kg;
            float wgt = fminf(dsT[(etid >> 4) + 1][(etid & 15) + 1], 20.f) / 20.f;
            acc += ce * wgt;
        }
    }
    rs[tid] = acc;
    __syncthreads();
    for (int q = 128; q > 0; q >>= 1) {
        if (tid < q) rs[tid] += rs[tid + q];
        __syncthreads();
    }
    if (tid == 0) {
        const int bid = (blockIdx.z * gridDim.y + blockIdx.y) * gridDim.x + blockIdx.x;
        partials[bid] = rs[0];
        bcnt[bid] = (unsigned int)nv;
    }
}

// ---------------------------------------------------------------------------
// k4: fixed-order reduce of 4096 partials + 4096 counts -> loss.
// ---------------------------------------------------------------------------
__global__ __launch_bounds__(256) void k4_kernel(const float* __restrict__ partials,
                                                 const unsigned int* __restrict__ bcnt,
                                                 float* __restrict__ out) {
    __shared__ float r1[256];
    __shared__ unsigned int r2[256];
    const int tid = threadIdx.x;
    float s = 0.f;
    unsigned int c = 0u;
#pragma unroll
    for (int q = 0; q < NT3 / 256; ++q) {
        s += partials[tid + q * 256];
        c += bcnt[tid + q * 256];
    }
    r1[tid] = s; r2[tid] = c;
    __syncthreads();
    for (int q = 128; q > 0; q >>= 1) {
        if (tid < q) { r1[tid] += r1[tid + q]; r2[tid] += r2[tid + q]; }
        __syncthreads();
    }
    if (tid == 0) out[0] = r1[0] / fmaxf((float)r2[0], 1.f);
}

extern "C" void kernel_launch(void* const* d_in, const int* in_sizes, int n_in,
                              void* d_out, int out_size, void* d_ws, size_t ws_size,
                              hipStream_t stream) {
    const float* logits = (const float*)d_in[0];
    const int* target = (const int*)d_in[1];
    float* out = (float*)d_out;

    float* fws = (float*)d_ws;
    float* distb = fws;                         // NPIX floats
    float* klb = fws + NPIX;                    // NPIX floats
    float* lsem = fws + 2 * (size_t)NPIX;       // NPIX floats
    unsigned int* hist = (unsigned int*)(fws + 3 * (size_t)NPIX);   // NREP*HSTRIDE
    float* partials = (float*)(hist + NREP * HSTRIDE);              // NT3
    unsigned int* bcnt = (unsigned int*)(partials + NT3);           // NT3
    unsigned int* maskw = bcnt + NT3;                               // NB*NWRD*NW

    // k1: bound (+zero hist) || LSE map (each LSE computed once)
    k1_kernel<<<NBND + NPIX / 256, 256, 0, stream>>>(target, logits, maskw, lsem, hist);
    // k2: vdist+rowmin || kl+hist (lsem-based, XCD-chunked kl rows)
    k2_kernel<<<NVD + NKL, 512, 0, stream>>>(maskw, logits, lsem, distb, klb, hist);
    // k3: parallel-eps + valid (LDS tiles) + in-block CE -> partials
    dim3 tiles(NW / TS, NH / TS, NB);
    k3_kernel<<<tiles, 256, 0, stream>>>(klb, distb, logits, lsem, hist,
                                         partials, bcnt);
    // k4: deterministic final reduce
    k4_kernel<<<1, 256, 0, stream>>>(partials, bcnt, out);
}